// Round 7
// baseline (545.874 us; speedup 1.0000x reference)
//
#include <hip/hip_runtime.h>
#include <hip/hip_bf16.h>
#include <math.h>

// ---------------------------------------------------------------------------
// B=2, S=4096, D=256, IN=768, N_BASIS=8, spline grid h=0.4
// view_emb adds a row-constant to pre-softmax scores -> cancelled -> unused.
// Softmax without max-subtraction: |q.k|/16 <= ~1.7 -> exp in [0.2,5.5].
// Scores GEMM writes unnormalized bf16 P = exp(acc/16) + lpart row partials;
// resid_ln reduces lpart and normalizes. KAN basis is NEVER materialized:
// the KAN GEMM generates A-tiles in-kernel (f-major K: k = f*768 + i, each
// BK=32 tile one channel; uniform knots -> basis f = cardinal cubic
// B3(2.5x + 5.5 - f), channel 8 = silu). QKV likewise casts tok fp32->bf16
// in-kernel (no tokb round trip).
// ---------------------------------------------------------------------------

typedef __hip_bfloat16 bf16;
using bf16x8 = __attribute__((ext_vector_type(8))) __bf16;
using f32x4  = __attribute__((ext_vector_type(4))) float;

__device__ __forceinline__ void load_lds16(const void* g, void* l) {
  __builtin_amdgcn_global_load_lds((__attribute__((address_space(1))) void*)g,
                                   (__attribute__((address_space(3))) void*)l,
                                   16, 0, 0);
}

__device__ __forceinline__ float wave_sum(float v) {
#pragma unroll
  for (int o = 32; o > 0; o >>= 1) v += __shfl_down(v, o, 64);
  return v;
}

// ---------------------------------------------------------------------------
// bf16 MFMA GEMM, BT form (both operands DMA-staged):
// C[m,n] = f(scale * sum_k A[m,k]*B[n,k] + bias[n]); f=exp if EXP (+lpart).
// 128x128 block, BK=32, 4 waves 2x2, 4x4 frags of 16x16x32; XOR-swizzled
// LDS granules -> conflict-free ds_read_b128. z = (hi<<zshift)|lo with
// separate A/B strides (batch x split-K).
// ---------------------------------------------------------------------------
template <typename OutT, bool EXP>
__global__ __launch_bounds__(256) void mfma_gemm_bt(
    const bf16* __restrict__ A, const bf16* __restrict__ B,
    const float* __restrict__ bias, OutT* __restrict__ C,
    float* __restrict__ lpart, int K, int lda, int ldb, int ldc, int zshift,
    size_t zAh, size_t zAl, size_t zBh, size_t zBl, size_t zC, size_t zL,
    float scale) {
  __shared__ __align__(16) bf16 As[4096];
  __shared__ __align__(16) bf16 Bs[4096];
  const int tid = (int)threadIdx.x;
  const int lane = tid & 63;
  const int w = tid >> 6;
  const int m0 = (int)blockIdx.y << 7;
  const int n0 = (int)blockIdx.x << 7;
  const size_t z = blockIdx.z;
  const size_t zlo = z & (((size_t)1 << zshift) - 1);
  A += (z >> zshift) * zAh + zlo * zAl;
  B += (z >> zshift) * zBh + zlo * zBl;
  C += z * zC;
  if (EXP) lpart += z * zL;

  const int srow = lane >> 2;
  const int qg = (lane & 3) ^ ((lane >> 3) & 3);
  const int ci0 = w, ci1 = w + 4;
  const bf16* gA0 = A + (size_t)(m0 + ci0 * 16 + srow) * lda + qg * 8;
  const bf16* gA1 = A + (size_t)(m0 + ci1 * 16 + srow) * lda + qg * 8;
  const bf16* gB0 = B + (size_t)(n0 + ci0 * 16 + srow) * ldb + qg * 8;
  const bf16* gB1 = B + (size_t)(n0 + ci1 * 16 + srow) * ldb + qg * 8;
  bf16* lA0 = As + ci0 * 512;
  bf16* lA1 = As + ci1 * 512;
  bf16* lB0 = Bs + ci0 * 512;
  bf16* lB1 = Bs + ci1 * 512;

  const int m15 = lane & 15, quad = lane >> 4;
  const int fq = quad ^ ((m15 >> 1) & 3);
  const int aoff = m15 * 32 + fq * 8;
  const bf16* pA = As + ((w >> 1) << 11) + aoff;
  const bf16* pB = Bs + ((w & 1) << 11) + aoff;

  f32x4 acc[4][4];
#pragma unroll
  for (int mi = 0; mi < 4; ++mi)
#pragma unroll
    for (int ni = 0; ni < 4; ++ni) acc[mi][ni] = (f32x4)(0.0f);

  for (int k0 = 0; k0 < K; k0 += 32) {
    load_lds16(gA0, lA0);
    load_lds16(gA1, lA1);
    load_lds16(gB0, lB0);
    load_lds16(gB1, lB1);
    gA0 += 32; gA1 += 32; gB0 += 32; gB1 += 32;
    __syncthreads();
    bf16x8 av[4], bv[4];
#pragma unroll
    for (int i = 0; i < 4; ++i) {
      av[i] = *(const bf16x8*)(pA + i * 512);
      bv[i] = *(const bf16x8*)(pB + i * 512);
    }
#pragma unroll
    for (int mi = 0; mi < 4; ++mi)
#pragma unroll
      for (int ni = 0; ni < 4; ++ni)
        acc[mi][ni] = __builtin_amdgcn_mfma_f32_16x16x32_bf16(
            av[mi], bv[ni], acc[mi][ni], 0, 0, 0);
    __syncthreads();
  }

  const int crow = m0 + ((w >> 1) << 6) + quad * 4;
  const int ccol = n0 + ((w & 1) << 6) + m15;
  float rs[4][4] = {};
#pragma unroll
  for (int ni = 0; ni < 4; ++ni) {
    const int col = ccol + ni * 16;
    const float bb = bias ? bias[col] : 0.0f;
#pragma unroll
    for (int mi = 0; mi < 4; ++mi) {
#pragma unroll
      for (int i = 0; i < 4; ++i) {
        const int row = crow + mi * 16 + i;
        float v = acc[mi][ni][i] * scale + bb;
        if constexpr (EXP) {
          v = __expf(v);
          rs[mi][i] += v;
        }
        if constexpr (sizeof(OutT) == 2)
          C[(size_t)row * ldc + col] = __float2bfloat16(v);
        else
          C[(size_t)row * ldc + col] = v;
      }
    }
  }
  if constexpr (EXP) {
    const int ch = ((int)blockIdx.x << 1) | (w & 1);
#pragma unroll
    for (int mi = 0; mi < 4; ++mi)
#pragma unroll
      for (int i = 0; i < 4; ++i) {
        float sv = rs[mi][i];
        sv += __shfl_xor(sv, 1);
        sv += __shfl_xor(sv, 2);
        sv += __shfl_xor(sv, 4);
        sv += __shfl_xor(sv, 8);
        if (m15 == 0)
          lpart[(size_t)ch * 4096 + crow + mi * 16 + i] = sv;
      }
  }
}

// ---------------------------------------------------------------------------
// MFMA GEMM with GENERATED A-tiles (no A in HBM):
//   GEN=1: A[m,k] = bf16(X[m,k])           (QKV: cast tok fp32 -> bf16)
//   GEN=2: A[m,k], k=f*768+i: f<8 -> B3(2.5*X[m,i]+5.5-f); f=8 -> silu(X[m,i])
// B DMA-staged as in mfma_gemm_bt. Same fragment/swizzle layout: thread t
// computes row t>>1, cols (t&1)*16..+15, ds_writes two b128 granules at
// physical granule g ^ swz(row).
// ---------------------------------------------------------------------------
template <int GEN, typename OutT>
__global__ __launch_bounds__(256) void mfma_gemm_genA(
    const float* __restrict__ X0, const float* __restrict__ X1,
    const float* __restrict__ X2, int ldx, const bf16* __restrict__ B,
    const float* __restrict__ bias, OutT* __restrict__ C, int Kslice,
    int ldb, int ldc, int zshift, size_t zBl, size_t zC, float scale) {
  __shared__ __align__(16) bf16 As[4096];
  __shared__ __align__(16) bf16 Bs[4096];
  const int tid = (int)threadIdx.x;
  const int lane = tid & 63;
  const int w = tid >> 6;
  const int m0 = (int)blockIdx.y << 7;
  const int n0 = (int)blockIdx.x << 7;
  const size_t z = blockIdx.z;
  const size_t zlo = z & (((size_t)1 << zshift) - 1);
  B += zlo * zBl;
  C += z * zC;
  const int kofs = (int)zlo * Kslice;

  // B staging (DMA)
  const int srow = lane >> 2;
  const int qg = (lane & 3) ^ ((lane >> 3) & 3);
  const bf16* gB0 = B + (size_t)(n0 + w * 16 + srow) * ldb + qg * 8;
  const bf16* gB1 = B + (size_t)(n0 + (w + 4) * 16 + srow) * ldb + qg * 8;
  bf16* lB0 = Bs + w * 512;
  bf16* lB1 = Bs + (w + 4) * 512;

  // A generation setup
  const int arow = tid >> 1;            // 0..127
  const int seg = (tid & 1) << 4;       // col offset 0 / 16
  const int swz = ((arow & 15) >> 1) & 3;
  const int g0 = seg >> 3;              // granule 0 or 2
  bf16* aw0 = As + arow * 32 + ((g0 ^ swz) << 3);
  bf16* aw1 = As + arow * 32 + (((g0 + 1) ^ swz) << 3);
  const float* Xp;
  if constexpr (GEN == 1) {
    const int v = m0 >> 13;  // 8192 rows per view
    const float* Xs = v == 0 ? X0 : (v == 1 ? X1 : X2);
    Xp = Xs + (size_t)((m0 & 8191) + arow) * ldx + seg;
  } else {
    Xp = X0 + (size_t)(m0 + arow) * ldx + seg;
  }
  int f = kofs / 768;
  int ib = kofs - f * 768;

  // fragment pointers
  const int m15 = lane & 15, quad = lane >> 4;
  const int fqA = quad ^ ((m15 >> 1) & 3);
  const int aoff = m15 * 32 + fqA * 8;
  const bf16* pA = As + ((w >> 1) << 11) + aoff;
  const bf16* pB = Bs + ((w & 1) << 11) + aoff;

  f32x4 acc[4][4];
#pragma unroll
  for (int mi = 0; mi < 4; ++mi)
#pragma unroll
    for (int ni = 0; ni < 4; ++ni) acc[mi][ni] = (f32x4)(0.0f);

  for (int k0 = 0; k0 < Kslice; k0 += 32) {
    load_lds16(gB0, lB0);
    load_lds16(gB1, lB1);
    gB0 += 32; gB1 += 32;

    const float* xs = Xp + ib;
    const float4 q0 = *(const float4*)(xs);
    const float4 q1 = *(const float4*)(xs + 4);
    const float4 q2 = *(const float4*)(xs + 8);
    const float4 q3 = *(const float4*)(xs + 12);
    float xv[16] = {q0.x, q0.y, q0.z, q0.w, q1.x, q1.y, q1.z, q1.w,
                    q2.x, q2.y, q2.z, q2.w, q3.x, q3.y, q3.z, q3.w};
    union { bf16x8 v; bf16 e[8]; } u0, u1;
    if constexpr (GEN == 1) {
#pragma unroll
      for (int j = 0; j < 8; ++j) {
        u0.e[j] = __float2bfloat16(xv[j]);
        u1.e[j] = __float2bfloat16(xv[8 + j]);
      }
    } else {
      if (f < 8) {
        // cardinal cubic B-spline, t = (x - g_f)/h = 2.5x + 5.5 - f
        const float tofs = 5.5f - (float)f;
#pragma unroll
        for (int j = 0; j < 16; ++j) {
          const float t = fmaf(xv[j], 2.5f, tofs);
          const float tc = fminf(fmaxf(t, 0.0f), 4.0f);
          const float p2 = fmaxf(tc - 1.0f, 0.0f);
          const float p3 = fmaxf(tc - 2.0f, 0.0f);
          const float p4 = fmaxf(tc - 3.0f, 0.0f);
          const float val = (tc * tc * tc - 4.0f * p2 * p2 * p2 +
                             6.0f * p3 * p3 * p3 - 4.0f * p4 * p4 * p4) *
                            (1.0f / 6.0f);
          if (j < 8) u0.e[j] = __float2bfloat16(val);
          else u1.e[j - 8] = __float2bfloat16(val);
        }
      } else {
#pragma unroll
        for (int j = 0; j < 16; ++j) {
          const float val = xv[j] / (1.0f + __expf(-xv[j]));
          if (j < 8) u0.e[j] = __float2bfloat16(val);
          else u1.e[j - 8] = __float2bfloat16(val);
        }
      }
    }
    *(bf16x8*)aw0 = u0.v;
    *(bf16x8*)aw1 = u1.v;

    __syncthreads();  // drains B-DMA (vmcnt) + A ds_writes (lgkmcnt)
    bf16x8 av[4], bv[4];
#pragma unroll
    for (int i = 0; i < 4; ++i) {
      av[i] = *(const bf16x8*)(pA + i * 512);
      bv[i] = *(const bf16x8*)(pB + i * 512);
    }
#pragma unroll
    for (int mi = 0; mi < 4; ++mi)
#pragma unroll
      for (int ni = 0; ni < 4; ++ni)
        acc[mi][ni] = __builtin_amdgcn_mfma_f32_16x16x32_bf16(
            av[mi], bv[ni], acc[mi][ni], 0, 0, 0);
    __syncthreads();

    ib += 32;
    if (ib == 768) { ib = 0; ++f; }
  }

  const int crow = m0 + ((w >> 1) << 6) + quad * 4;
  const int ccol = n0 + ((w & 1) << 6) + m15;
#pragma unroll
  for (int ni = 0; ni < 4; ++ni) {
    const int col = ccol + ni * 16;
    const float bb = bias ? bias[col] : 0.0f;
#pragma unroll
    for (int mi = 0; mi < 4; ++mi) {
#pragma unroll
      for (int i = 0; i < 4; ++i) {
        const int row = crow + mi * 16 + i;
        const float v = acc[mi][ni][i] * scale + bb;
        if constexpr (sizeof(OutT) == 2)
          C[(size_t)row * ldc + col] = __float2bfloat16(v);
        else
          C[(size_t)row * ldc + col] = v;
      }
    }
  }
}

// ---------------------------------------------------------------------------
// residual + LayerNorm from split-K PV partials and lpart row sums
// ---------------------------------------------------------------------------
__global__ __launch_bounds__(256) void resid_ln_kernel(
    const float* __restrict__ attp, const float* __restrict__ lpart,
    const float* __restrict__ tok, const float* __restrict__ gamma,
    const float* __restrict__ beta, float* __restrict__ x, int vIdx) {
  __shared__ float red[4];
  __shared__ float sinvl;
  const int n = (int)blockIdx.x;  // 0..8191 ; b = n>>12
  const int d = (int)threadIdx.x;
  const int b = n >> 12, r = n & 4095;
  float ls = 0.f;
  if (d < 64) ls = lpart[((size_t)(b * 64 + d)) * 4096 + r];
  ls = wave_sum(ls);
  if (d == 0) sinvl = 1.0f / ls;
  const size_t abase = (size_t)(b * 4) * 1048576 + (size_t)r * 256 + d;
  const float asum = attp[abase] + attp[abase + 1048576] +
                     attp[abase + 2097152] + attp[abase + 3145728];
  __syncthreads();
  const float y = asum * sinvl + tok[(size_t)n * 256 + d];
  float s = wave_sum(y);
  if ((d & 63) == 0) red[d >> 6] = s;
  __syncthreads();
  const float mu = (red[0] + red[1] + red[2] + red[3]) * (1.0f / 256.0f);
  __syncthreads();
  const float c = y - mu;
  float s2 = wave_sum(c * c);
  if ((d & 63) == 0) red[d >> 6] = s2;
  __syncthreads();
  const float var = (red[0] + red[1] + red[2] + red[3]) * (1.0f / 256.0f);
  const float rstd = rsqrtf(var + 1e-5f);
  x[(size_t)n * 768 + vIdx * 256 + d] = c * rstd * gamma[d] + beta[d];
}

// ---------------------------------------------------------------------------
// f-major Wmat: Wmat[o][f*768+i] = sw[o,i,f]*scaler[o,i] (f<8); f=8 -> bw
// ---------------------------------------------------------------------------
__global__ __launch_bounds__(256) void prep_w(
    const float* __restrict__ bw, const float* __restrict__ sw,
    const float* __restrict__ scaler, bf16* __restrict__ Wmat) {
  const int o = blockIdx.x;
  bf16* p = Wmat + (size_t)o * 6912;
  for (int ii = 0; ii < 3; ++ii) {
    const int i = ii * 256 + (int)threadIdx.x;
    const float s = scaler[(size_t)o * 768 + i];
    const float* swp = sw + ((size_t)o * 768 + i) * 8;
#pragma unroll
    for (int f = 0; f < 8; ++f) p[f * 768 + i] = __float2bfloat16(swp[f] * s);
    p[6144 + i] = __float2bfloat16(bw[(size_t)o * 768 + i]);
  }
}

__global__ __launch_bounds__(256) void prep_qkvw(
    const float* __restrict__ wq, const float* __restrict__ wk,
    const float* __restrict__ wv, const float* __restrict__ bq,
    const float* __restrict__ bk, const float* __restrict__ bv,
    bf16* __restrict__ wqkvb, float* __restrict__ bqkv) {
  const int idx = blockIdx.x * 256 + (int)threadIdx.x;
  const int row = idx >> 8, col = idx & 255;
  const float* src = row < 256 ? wq : (row < 512 ? wk : wv);
  wqkvb[idx] = __float2bfloat16(src[((row & 255) << 8) + col]);
  if (idx < 768)
    bqkv[idx] = idx < 256 ? bq[idx] : (idx < 512 ? bk[idx - 256] : bv[idx - 512]);
}

// vT[z][d][s] = qkv[z*4096+s][512+d]
__global__ __launch_bounds__(256) void transpose_v(
    const bf16* __restrict__ qkv, bf16* __restrict__ vT) {
  __shared__ bf16 tle[64][65];
  const int s0 = blockIdx.x << 6, d0 = blockIdx.y << 6, z = blockIdx.z;
  const int tid = (int)threadIdx.x;
  const int c = tid & 63, rr = tid >> 6;
  for (int r = 0; r < 64; r += 4)
    tle[r + rr][c] = qkv[(size_t)(z * 4096 + s0 + r + rr) * 768 + 512 + d0 + c];
  __syncthreads();
  for (int r = 0; r < 64; r += 4)
    vT[(size_t)z * 1048576 + (size_t)(d0 + r + rr) * 4096 + s0 + c] =
        tle[c][r + rr];
}

__global__ __launch_bounds__(256) void combine4_kernel(
    const float4* __restrict__ p, float4* __restrict__ out) {
  const int idx = blockIdx.x * 256 + (int)threadIdx.x;
  const float4 a = p[idx];
  const float4 b = p[idx + 524288];
  const float4 c = p[idx + 1048576];
  const float4 d = p[idx + 1572864];
  out[idx] =
      make_float4(a.x + b.x + c.x + d.x, a.y + b.y + c.y + d.y,
                  a.z + b.z + c.z + d.z, a.w + b.w + c.w + d.w);
}

// ---------------------------------------------------------------------------
extern "C" void kernel_launch(void* const* d_in, const int* in_sizes, int n_in,
                              void* d_out, int out_size, void* d_ws,
                              size_t ws_size, hipStream_t stream) {
  const float* tok[3] = {(const float*)d_in[0], (const float*)d_in[1],
                         (const float*)d_in[2]};
  const float* wq = (const float*)d_in[3];
  const float* bq = (const float*)d_in[4];
  const float* wk = (const float*)d_in[5];
  const float* bk = (const float*)d_in[6];
  const float* wv = (const float*)d_in[7];
  const float* bv = (const float*)d_in[8];
  // d_in[9] view_emb unused (softmax-invariant)
  const float* lng[3] = {(const float*)d_in[10], (const float*)d_in[12],
                         (const float*)d_in[14]};
  const float* lnb[3] = {(const float*)d_in[11], (const float*)d_in[13],
                         (const float*)d_in[15]};
  const float* bw = (const float*)d_in[16];
  const float* sw = (const float*)d_in[17];
  const float* scaler = (const float*)d_in[18];

  // workspace layout (bytes), total ~182.2 MB. pout aliases attp (dead
  // after last resid_ln, before the KAN GEMM).
  char* w8 = (char*)d_ws;
  bf16* qkv = (bf16*)(w8 + 0);               // [3*8192,768]    37.75 MB
  bf16* vT = (bf16*)(w8 + 37748736);         // [6][256][4096]  12.58 MB
  bf16* Pb = (bf16*)(w8 + 50331648);         // [2][4096,4096]  67.11 MB
  float* lpart = (float*)(w8 + 117440512);   // [2][64][4096]    2.10 MB
  float* attp = (float*)(w8 + 119537664);    // [8][4096,256]   33.55 MB
  float* x = (float*)(w8 + 153092096);       // [8192,768]      25.17 MB
  bf16* Wmat = (bf16*)(w8 + 178257920);      // [256,6912]       3.54 MB
  bf16* wqkvb = (bf16*)(w8 + 181796864);     // [768,256]        0.39 MB
  float* bqkv = (float*)(w8 + 182190080);    // [768]
  float* pout = attp;                        // [4][8192,256] alias

  prep_w<<<256, 256, 0, stream>>>(bw, sw, scaler, Wmat);
  prep_qkvw<<<768, 256, 0, stream>>>(wq, wk, wv, bq, bk, bv, wqkvb, bqkv);

  // QKV all views, A generated (fp32 tok cast in-kernel):
  // [24576,256] @ [768,256]^T + bias -> qkv bf16
  mfma_gemm_genA<1, bf16><<<dim3(6, 192, 1), 256, 0, stream>>>(
      tok[0], tok[1], tok[2], 256, wqkvb, bqkv, qkv, 256, 256, 768, 0, 0, 0,
      1.0f);
  transpose_v<<<dim3(64, 4, 6), 256, 0, stream>>>(qkv, vT);

  for (int v = 0; v < 3; ++v) {
    const bf16* qb = qkv + (size_t)(2 * v) * 4096 * 768;
    // scores both batches (z=2): P = exp(q@k^T/16) bf16 + lpart partials
    mfma_gemm_bt<bf16, true><<<dim3(32, 32, 2), 256, 0, stream>>>(
        qb, qb + 256, nullptr, Pb, lpart, 256, 768, 768, 4096, 1, 0, 3145728,
        0, 3145728, 16777216, 262144, 0.0625f);
    // PV split-K=4 x batch (z=8): attp[z] = P-slice @ vT-slice^T
    mfma_gemm_bt<float, false><<<dim3(2, 32, 8), 256, 0, stream>>>(
        Pb, vT + (size_t)(2 * v) * 1048576, nullptr, attp, nullptr, 1024,
        4096, 4096, 256, 2, 16777216, 1024, 1048576, 1024, 1048576, 0, 1.0f);
    resid_ln_kernel<<<8192, 256, 0, stream>>>(attp, lpart, tok[v], lng[v],
                                              lnb[v], x, v);
  }

  // KAN split-K=4 (z=4), A generated in-kernel (splines+silu from x):
  // [8192, 6912] @ Wmat[256,6912]^T -> pout[z]
  mfma_gemm_genA<2, float><<<dim3(2, 64, 4), 256, 0, stream>>>(
      x, x, x, 768, Wmat, nullptr, pout, 1728, 6912, 256, 2, 1728, 2097152,
      1.0f);
  combine4_kernel<<<2048, 256, 0, stream>>>((const float4*)pout,
                                            (float4*)d_out);
}

// Round 9
// 528.741 us; speedup vs baseline: 1.0324x; 1.0324x over previous
//
#include <hip/hip_runtime.h>
#include <hip/hip_bf16.h>
#include <math.h>

// ---------------------------------------------------------------------------
// B=2, S=4096, D=256, IN=768, N_BASIS=8, spline grid h=0.4
// view_emb adds a row-constant to pre-softmax scores -> cancelled -> unused.
// Softmax without max-subtraction: |q.k|/16 <= ~1.7 -> exp in [0.2,5.5].
// Scores GEMM writes unnormalized bf16 P = exp(acc/16) + lpart row partials.
// resid_ln reduces lpart, normalizes, LayerNorms, and (fused path) directly
// emits the 9 KAN basis channels (closed-form cardinal cubic B3(2.5x+5.5-f),
// validated R7; ch 8 = silu). Fallback = byte-identical R6 layout.
// R8 NaN root cause: lpart/attp overlapped Pb (offsets not shifted when tokb
// was reintroduced). Fixed: lpart @130,023,424 directly after Pb.
// ---------------------------------------------------------------------------

typedef __hip_bfloat16 bf16;
using bf16x8 = __attribute__((ext_vector_type(8))) __bf16;
using f32x4  = __attribute__((ext_vector_type(4))) float;

__device__ __forceinline__ void load_lds16(const void* g, void* l) {
  __builtin_amdgcn_global_load_lds((__attribute__((address_space(1))) void*)g,
                                   (__attribute__((address_space(3))) void*)l,
                                   16, 0, 0);
}

__device__ __forceinline__ float wave_sum(float v) {
#pragma unroll
  for (int o = 32; o > 0; o >>= 1) v += __shfl_down(v, o, 64);
  return v;
}

// closed-form cardinal cubic B-spline segment (validated R7, absmax 0.0156)
__device__ __forceinline__ float b3_cardinal(float x, float tofs) {
  const float t = fmaf(x, 2.5f, tofs);
  const float tc = fminf(fmaxf(t, 0.0f), 4.0f);
  const float p2 = fmaxf(tc - 1.0f, 0.0f);
  const float p3 = fmaxf(tc - 2.0f, 0.0f);
  const float p4 = fmaxf(tc - 3.0f, 0.0f);
  return (tc * tc * tc - 4.0f * p2 * p2 * p2 + 6.0f * p3 * p3 * p3 -
          4.0f * p4 * p4 * p4) * (1.0f / 6.0f);
}

// ---------------------------------------------------------------------------
// bf16 MFMA GEMM, BT form (both operands DMA-staged):
// C[m,n] = f(scale * sum_k A[m,k]*B[n,k] + bias[n]); f=exp if EXP (+lpart).
// 128x128 block, BK=32, 4 waves 2x2, 4x4 frags of 16x16x32; XOR-swizzled
// LDS granules -> conflict-free ds_read_b128. z = (hi<<zshift)|lo with
// separate A/B strides (batch x split-K).
// ---------------------------------------------------------------------------
template <typename OutT, bool EXP>
__global__ __launch_bounds__(256) void mfma_gemm_bt(
    const bf16* __restrict__ A, const bf16* __restrict__ B,
    const float* __restrict__ bias, OutT* __restrict__ C,
    float* __restrict__ lpart, int K, int lda, int ldb, int ldc, int zshift,
    size_t zAh, size_t zAl, size_t zBh, size_t zBl, size_t zC, size_t zL,
    float scale) {
  __shared__ __align__(16) bf16 As[4096];
  __shared__ __align__(16) bf16 Bs[4096];
  const int tid = (int)threadIdx.x;
  const int lane = tid & 63;
  const int w = tid >> 6;
  const int m0 = (int)blockIdx.y << 7;
  const int n0 = (int)blockIdx.x << 7;
  const size_t z = blockIdx.z;
  const size_t zlo = z & (((size_t)1 << zshift) - 1);
  A += (z >> zshift) * zAh + zlo * zAl;
  B += (z >> zshift) * zBh + zlo * zBl;
  C += z * zC;
  if (EXP) lpart += z * zL;

  const int srow = lane >> 2;
  const int qg = (lane & 3) ^ ((lane >> 3) & 3);
  const int ci0 = w, ci1 = w + 4;
  const bf16* gA0 = A + (size_t)(m0 + ci0 * 16 + srow) * lda + qg * 8;
  const bf16* gA1 = A + (size_t)(m0 + ci1 * 16 + srow) * lda + qg * 8;
  const bf16* gB0 = B + (size_t)(n0 + ci0 * 16 + srow) * ldb + qg * 8;
  const bf16* gB1 = B + (size_t)(n0 + ci1 * 16 + srow) * ldb + qg * 8;
  bf16* lA0 = As + ci0 * 512;
  bf16* lA1 = As + ci1 * 512;
  bf16* lB0 = Bs + ci0 * 512;
  bf16* lB1 = Bs + ci1 * 512;

  const int m15 = lane & 15, quad = lane >> 4;
  const int fq = quad ^ ((m15 >> 1) & 3);
  const int aoff = m15 * 32 + fq * 8;
  const bf16* pA = As + ((w >> 1) << 11) + aoff;
  const bf16* pB = Bs + ((w & 1) << 11) + aoff;

  f32x4 acc[4][4];
#pragma unroll
  for (int mi = 0; mi < 4; ++mi)
#pragma unroll
    for (int ni = 0; ni < 4; ++ni) acc[mi][ni] = (f32x4)(0.0f);

  for (int k0 = 0; k0 < K; k0 += 32) {
    load_lds16(gA0, lA0);
    load_lds16(gA1, lA1);
    load_lds16(gB0, lB0);
    load_lds16(gB1, lB1);
    gA0 += 32; gA1 += 32; gB0 += 32; gB1 += 32;
    __syncthreads();
    bf16x8 av[4], bv[4];
#pragma unroll
    for (int i = 0; i < 4; ++i) {
      av[i] = *(const bf16x8*)(pA + i * 512);
      bv[i] = *(const bf16x8*)(pB + i * 512);
    }
#pragma unroll
    for (int mi = 0; mi < 4; ++mi)
#pragma unroll
      for (int ni = 0; ni < 4; ++ni)
        acc[mi][ni] = __builtin_amdgcn_mfma_f32_16x16x32_bf16(
            av[mi], bv[ni], acc[mi][ni], 0, 0, 0);
    __syncthreads();
  }

  const int crow = m0 + ((w >> 1) << 6) + quad * 4;
  const int ccol = n0 + ((w & 1) << 6) + m15;
  float rs[4][4] = {};
#pragma unroll
  for (int ni = 0; ni < 4; ++ni) {
    const int col = ccol + ni * 16;
    const float bb = bias ? bias[col] : 0.0f;
#pragma unroll
    for (int mi = 0; mi < 4; ++mi) {
#pragma unroll
      for (int i = 0; i < 4; ++i) {
        const int row = crow + mi * 16 + i;
        float v = acc[mi][ni][i] * scale + bb;
        if constexpr (EXP) {
          v = __expf(v);
          rs[mi][i] += v;
        }
        if constexpr (sizeof(OutT) == 2)
          C[(size_t)row * ldc + col] = __float2bfloat16(v);
        else
          C[(size_t)row * ldc + col] = v;
      }
    }
  }
  if constexpr (EXP) {
    const int ch = ((int)blockIdx.x << 1) | (w & 1);
#pragma unroll
    for (int mi = 0; mi < 4; ++mi)
#pragma unroll
      for (int i = 0; i < 4; ++i) {
        float sv = rs[mi][i];
        sv += __shfl_xor(sv, 1);
        sv += __shfl_xor(sv, 2);
        sv += __shfl_xor(sv, 4);
        sv += __shfl_xor(sv, 8);
        if (m15 == 0)
          lpart[(size_t)ch * 4096 + crow + mi * 16 + i] = sv;
      }
  }
}

// ---------------------------------------------------------------------------
// residual + LayerNorm from split-K PV partials and lpart row sums.
// FUSE=true : emit 9 bf16 KAN basis channels directly (no x buffer).
// FUSE=false: write x fp32 (fallback; basis_kernel runs later).
// ---------------------------------------------------------------------------
template <bool FUSE>
__global__ __launch_bounds__(256) void resid_ln_kernel(
    const float* __restrict__ attp, const float* __restrict__ lpart,
    const float* __restrict__ tok, const float* __restrict__ gamma,
    const float* __restrict__ beta, float* __restrict__ xout,
    bf16* __restrict__ basis, int vIdx) {
  __shared__ float red[4];
  __shared__ float sinvl;
  __shared__ __align__(16) bf16 st[2304];  // 256 elems x 9 channels
  const int n = (int)blockIdx.x;  // 0..8191 ; b = n>>12
  const int d = (int)threadIdx.x;
  const int b = n >> 12, r = n & 4095;
  float ls = 0.f;
  if (d < 64) ls = lpart[((size_t)(b * 64 + d)) * 4096 + r];
  ls = wave_sum(ls);
  if (d == 0) sinvl = 1.0f / ls;
  const size_t abase = (size_t)(b * 4) * 1048576 + (size_t)r * 256 + d;
  const float asum = attp[abase] + attp[abase + 1048576] +
                     attp[abase + 2097152] + attp[abase + 3145728];
  __syncthreads();
  const float y = asum * sinvl + tok[(size_t)n * 256 + d];
  float s = wave_sum(y);
  if ((d & 63) == 0) red[d >> 6] = s;
  __syncthreads();
  const float mu = (red[0] + red[1] + red[2] + red[3]) * (1.0f / 256.0f);
  __syncthreads();
  const float c = y - mu;
  float s2 = wave_sum(c * c);
  if ((d & 63) == 0) red[d >> 6] = s2;
  __syncthreads();
  const float var = (red[0] + red[1] + red[2] + red[3]) * (1.0f / 256.0f);
  const float rstd = rsqrtf(var + 1e-5f);
  const float val = c * rstd * gamma[d] + beta[d];
  if constexpr (!FUSE) {
    xout[(size_t)n * 768 + vIdx * 256 + d] = val;
  } else {
#pragma unroll
    for (int f = 0; f < 8; ++f)
      st[d * 9 + f] = __float2bfloat16(b3_cardinal(val, 5.5f - (float)f));
    st[d * 9 + 8] = __float2bfloat16(val / (1.0f + __expf(-val)));
    __syncthreads();
    // basis row slice: 256 elems x 9 ch = 4608 B, float4-aligned
    float4* gb = (float4*)((char*)basis + (size_t)n * 13824 + vIdx * 4608);
    const float4* sb = (const float4*)st;
    gb[d] = sb[d];
    if (d < 32) gb[256 + d] = sb[256 + d];
  }
}

// ---------------------------------------------------------------------------
// Wmat[o][i*9+f]: f<8 -> sw[o,i,f]*scaler[o,i]; f=8 -> bw[o,i]
// ---------------------------------------------------------------------------
__global__ __launch_bounds__(256) void prep_w(
    const float* __restrict__ bw, const float* __restrict__ sw,
    const float* __restrict__ scaler, bf16* __restrict__ Wmat) {
  const int o = blockIdx.x;
  for (int ii = 0; ii < 3; ++ii) {
    const int i = ii * 256 + (int)threadIdx.x;
    const float s = scaler[(size_t)o * 768 + i];
    bf16* p = Wmat + (size_t)o * 6912 + i * 9;
    const float* swp = sw + ((size_t)o * 768 + i) * 8;
#pragma unroll
    for (int f = 0; f < 8; ++f) p[f] = __float2bfloat16(swp[f] * s);
    p[8] = __float2bfloat16(bw[(size_t)o * 768 + i]);
  }
}

__global__ __launch_bounds__(256) void prep_qkvw(
    const float* __restrict__ wq, const float* __restrict__ wk,
    const float* __restrict__ wv, const float* __restrict__ bq,
    const float* __restrict__ bk, const float* __restrict__ bv,
    bf16* __restrict__ wqkvb, float* __restrict__ bqkv) {
  const int idx = blockIdx.x * 256 + (int)threadIdx.x;
  const int row = idx >> 8, col = idx & 255;
  const float* src = row < 256 ? wq : (row < 512 ? wk : wv);
  wqkvb[idx] = __float2bfloat16(src[((row & 255) << 8) + col]);
  if (idx < 768)
    bqkv[idx] = idx < 256 ? bq[idx] : (idx < 512 ? bk[idx - 256] : bv[idx - 512]);
}

__global__ __launch_bounds__(256) void cast_tok3(
    const float4* __restrict__ t0, const float4* __restrict__ t1,
    const float4* __restrict__ t2, bf16* __restrict__ dst) {
  const int vv = blockIdx.y;
  const float4* src = vv == 0 ? t0 : (vv == 1 ? t1 : t2);
  const int idx = blockIdx.x * 256 + (int)threadIdx.x;
  const float4 val = src[idx];
  bf16* p = dst + (size_t)vv * 2097152 + (size_t)idx * 4;
  p[0] = __float2bfloat16(val.x);
  p[1] = __float2bfloat16(val.y);
  p[2] = __float2bfloat16(val.z);
  p[3] = __float2bfloat16(val.w);
}

// vT[z][d][s] = qkv[z*4096+s][512+d]
__global__ __launch_bounds__(256) void transpose_v(
    const bf16* __restrict__ qkv, bf16* __restrict__ vT) {
  __shared__ bf16 tle[64][65];
  const int s0 = blockIdx.x << 6, d0 = blockIdx.y << 6, z = blockIdx.z;
  const int tid = (int)threadIdx.x;
  const int c = tid & 63, rr = tid >> 6;
  for (int r = 0; r < 64; r += 4)
    tle[r + rr][c] = qkv[(size_t)(z * 4096 + s0 + r + rr) * 768 + 512 + d0 + c];
  __syncthreads();
  for (int r = 0; r < 64; r += 4)
    vT[(size_t)z * 1048576 + (size_t)(d0 + r + rr) * 4096 + s0 + c] =
        tle[c][r + rr];
}

// ---------------------------------------------------------------------------
// fallback basis: basis[n][i*9+f] from x (Cox-de-Boor, proven R6)
// ---------------------------------------------------------------------------
__global__ __launch_bounds__(256) void basis_kernel(
    const float* __restrict__ x, bf16* __restrict__ basis) {
  const int i = blockIdx.x * 256 + (int)threadIdx.x;  // 0..767
  const int n = blockIdx.y;
  const float xv = x[(size_t)n * 768 + i];
  float b[11];
#pragma unroll
  for (int m = 0; m < 11; ++m) {
    const float g0 = 0.4f * (float)(m - 3) - 1.0f;
    const float g1 = 0.4f * (float)(m - 2) - 1.0f;
    b[m] = (xv >= g0 && xv < g1) ? 1.0f : 0.0f;
  }
#pragma unroll
  for (int k = 1; k <= 3; ++k) {
    const float inv = 1.0f / (0.4f * (float)k);
#pragma unroll
    for (int m = 0; m + k < 11; ++m) {
      const float gm = 0.4f * (float)(m - 3) - 1.0f;
      const float gmk1 = 0.4f * (float)(m + k - 2) - 1.0f;
      b[m] = (xv - gm) * inv * b[m] + (gmk1 - xv) * inv * b[m + 1];
    }
  }
  bf16* p = basis + (size_t)n * 6912 + i * 9;
#pragma unroll
  for (int f = 0; f < 8; ++f) p[f] = __float2bfloat16(b[f]);
  p[8] = __float2bfloat16(xv / (1.0f + __expf(-xv)));
}

__global__ __launch_bounds__(256) void combine4_kernel(
    const float4* __restrict__ p, float4* __restrict__ out) {
  const int idx = blockIdx.x * 256 + (int)threadIdx.x;
  const float4 a = p[idx];
  const float4 b = p[idx + 524288];
  const float4 c = p[idx + 1048576];
  const float4 d = p[idx + 1572864];
  out[idx] =
      make_float4(a.x + b.x + c.x + d.x, a.y + b.y + c.y + d.y,
                  a.z + b.z + c.z + d.z, a.w + b.w + c.w + d.w);
}

// ---------------------------------------------------------------------------
extern "C" void kernel_launch(void* const* d_in, const int* in_sizes, int n_in,
                              void* d_out, int out_size, void* d_ws,
                              size_t ws_size, hipStream_t stream) {
  const float* tok[3] = {(const float*)d_in[0], (const float*)d_in[1],
                         (const float*)d_in[2]};
  const float* wq = (const float*)d_in[3];
  const float* bq = (const float*)d_in[4];
  const float* wk = (const float*)d_in[5];
  const float* bk = (const float*)d_in[6];
  const float* wv = (const float*)d_in[7];
  const float* bv = (const float*)d_in[8];
  // d_in[9] view_emb unused (softmax-invariant)
  const float* lng[3] = {(const float*)d_in[10], (const float*)d_in[12],
                         (const float*)d_in[14]};
  const float* lnb[3] = {(const float*)d_in[11], (const float*)d_in[13],
                         (const float*)d_in[15]};
  const float* bw = (const float*)d_in[16];
  const float* sw = (const float*)d_in[17];
  const float* scaler = (const float*)d_in[18];

  // layout (bytes):
  //   tokb   @ 0            12,582,912
  //   qkv    @ 12,582,912   37,748,736
  //   vT     @ 50,331,648   12,582,912
  //   Pb     @ 62,914,560   67,108,864   (ends 130,023,424)
  //   lpart  @ 130,023,424   2,097,152
  //   attp   @ 132,120,576  33,554,432   (ends 165,675,008; pout aliases)
  // fused  : basis @165,675,008 (113,246,208), Wmat @278,921,216 -> needs
  //          282,856,448 B total.
  // fallback (== R6 proven): x @165,675,008 (25,165,824), basis aliases
  //          [0,113,246,208) (tokb..Pb dead by then), Wmat @190,840,832.
  const bool fused = ws_size >= 282856448ull;
  char* w8 = (char*)d_ws;
  bf16* tokb = (bf16*)(w8 + 0);
  bf16* qkv = (bf16*)(w8 + 12582912);
  bf16* vT = (bf16*)(w8 + 50331648);
  bf16* Pb = (bf16*)(w8 + 62914560);
  float* lpart = (float*)(w8 + 130023424);
  float* attp = (float*)(w8 + 132120576);
  float* pout = attp;  // [4][8192,256] alias (attp dead before KAN GEMM)
  float* x;
  bf16* basis;
  bf16* Wmat;
  if (fused) {
    x = nullptr;
    basis = (bf16*)(w8 + 165675008);
    Wmat = (bf16*)(w8 + 278921216);
  } else {
    x = (float*)(w8 + 165675008);
    basis = (bf16*)(w8 + 0);
    Wmat = (bf16*)(w8 + 190840832);
  }
  bf16* wqkvb = (bf16*)((char*)Wmat + 3538944);
  float* bqkv = (float*)((char*)wqkvb + 393216);

  prep_w<<<256, 256, 0, stream>>>(bw, sw, scaler, Wmat);
  prep_qkvw<<<768, 256, 0, stream>>>(wq, wk, wv, bq, bk, bv, wqkvb, bqkv);
  cast_tok3<<<dim3(2048, 3), 256, 0, stream>>>(
      (const float4*)tok[0], (const float4*)tok[1], (const float4*)tok[2],
      tokb);

  // QKV all views: [24576,256] @ [768,256]^T + bias -> qkv bf16
  mfma_gemm_bt<bf16, false><<<dim3(6, 192, 1), 256, 0, stream>>>(
      tokb, wqkvb, bqkv, qkv, nullptr, 256, 256, 256, 768, 1, 0, 0, 0, 0, 0,
      0, 1.0f);
  transpose_v<<<dim3(64, 4, 6), 256, 0, stream>>>(qkv, vT);

  for (int v = 0; v < 3; ++v) {
    const bf16* qb = qkv + (size_t)(2 * v) * 4096 * 768;
    // scores both batches (z=2): P = exp(q@k^T/16) bf16 + lpart partials
    mfma_gemm_bt<bf16, true><<<dim3(32, 32, 2), 256, 0, stream>>>(
        qb, qb + 256, nullptr, Pb, lpart, 256, 768, 768, 4096, 1, 0, 3145728,
        0, 3145728, 16777216, 262144, 0.0625f);
    // PV split-K=4 x batch (z=8): attp[z] = P-slice @ vT-slice^T
    mfma_gemm_bt<float, false><<<dim3(2, 32, 8), 256, 0, stream>>>(
        Pb, vT + (size_t)(2 * v) * 1048576, nullptr, attp, nullptr, 1024,
        4096, 4096, 256, 2, 16777216, 1024, 1048576, 1024, 1048576, 0, 1.0f);
    if (fused)
      resid_ln_kernel<true><<<8192, 256, 0, stream>>>(
          attp, lpart, tok[v], lng[v], lnb[v], nullptr, basis, v);
    else
      resid_ln_kernel<false><<<8192, 256, 0, stream>>>(
          attp, lpart, tok[v], lng[v], lnb[v], x, nullptr, v);
  }

  if (!fused) basis_kernel<<<dim3(3, 8192), 256, 0, stream>>>(x, basis);

  // KAN split-K=4 (z=4): pout[z] = basis[:,kh*1728+:1728] @ Wmat-part
  mfma_gemm_bt<float, false><<<dim3(2, 64, 4), 256, 0, stream>>>(
      basis, Wmat, nullptr, pout, nullptr, 1728, 6912, 6912, 256, 2, 0, 1728,
      0, 1728, 2097152, 0, 1.0f);
  combine4_kernel<<<2048, 256, 0, stream>>>((const float4*)pout,
                                            (float4*)d_out);
}

// Round 10
// 492.071 us; speedup vs baseline: 1.1093x; 1.0745x over previous
//
#include <hip/hip_runtime.h>
#include <hip/hip_bf16.h>
#include <math.h>

// ---------------------------------------------------------------------------
// B=2, S=4096, D=256, IN=768, N_BASIS=8, spline grid h=0.4
// view_emb adds a row-constant to pre-softmax scores -> cancelled -> unused.
// Softmax without max-subtraction: |q.k|/16 <= ~1.7 -> exp in [0.2,5.5].
// Scores GEMM writes unnormalized bf16 P = exp(acc/16) + lpart row partials.
// resid_ln reduces lpart, normalizes, LayerNorms, and (fused path) directly
// emits the 9 KAN basis channels (closed-form cardinal cubic B3(2.5x+5.5-f),
// validated R7; ch 8 = silu). R10: BK=64 GEMM (halves barrier drains, 8 DMAs
// in flight per wave) + KAN split-K=6 (pout in dead Pb region).
// ---------------------------------------------------------------------------

typedef __hip_bfloat16 bf16;
using bf16x8 = __attribute__((ext_vector_type(8))) __bf16;
using f32x4  = __attribute__((ext_vector_type(4))) float;

__device__ __forceinline__ void load_lds16(const void* g, void* l) {
  __builtin_amdgcn_global_load_lds((__attribute__((address_space(1))) void*)g,
                                   (__attribute__((address_space(3))) void*)l,
                                   16, 0, 0);
}

__device__ __forceinline__ float wave_sum(float v) {
#pragma unroll
  for (int o = 32; o > 0; o >>= 1) v += __shfl_down(v, o, 64);
  return v;
}

// closed-form cardinal cubic B-spline segment (validated R7)
__device__ __forceinline__ float b3_cardinal(float x, float tofs) {
  const float t = fmaf(x, 2.5f, tofs);
  const float tc = fminf(fmaxf(t, 0.0f), 4.0f);
  const float p2 = fmaxf(tc - 1.0f, 0.0f);
  const float p3 = fmaxf(tc - 2.0f, 0.0f);
  const float p4 = fmaxf(tc - 3.0f, 0.0f);
  return (tc * tc * tc - 4.0f * p2 * p2 * p2 + 6.0f * p3 * p3 * p3 -
          4.0f * p4 * p4 * p4) * (1.0f / 6.0f);
}

// ---------------------------------------------------------------------------
// bf16 MFMA GEMM, BT form, BK=64: C[m,n] = f(scale*sum_k A[m,k]B[n,k]+bias)
// f = exp if EXP (+lpart row partials). 128x128 block, 4 waves 2x2, 4x4
// frags of 16x16x32, two k-sub-steps per iteration (order == two BK=32
// steps, bitwise-identical accumulation). Staging: 16 chunks/operand of
// 8 rows x 64 cols; lane l stages row c*8+(l>>3), LDS slot l&7 holds
// logical granule (l&4)|((l&3)^((l>>4)&3)) -> fragment ds_read_b128 at
// phys = sub*4 + (quad^((m15>>1)&3)) is conflict-free (same profile as the
// proven BK=32 swizzle). z = (hi<<zshift)|lo with separate A/B strides.
// ---------------------------------------------------------------------------
template <typename OutT, bool EXP>
__global__ __launch_bounds__(256) void mfma_gemm_bt(
    const bf16* __restrict__ A, const bf16* __restrict__ B,
    const float* __restrict__ bias, OutT* __restrict__ C,
    float* __restrict__ lpart, int K, int lda, int ldb, int ldc, int zshift,
    size_t zAh, size_t zAl, size_t zBh, size_t zBl, size_t zC, size_t zL,
    float scale) {
  __shared__ __align__(16) bf16 As[8192];  // 128 x 64
  __shared__ __align__(16) bf16 Bs[8192];
  const int tid = (int)threadIdx.x;
  const int lane = tid & 63;
  const int w = tid >> 6;
  const int m0 = (int)blockIdx.y << 7;
  const int n0 = (int)blockIdx.x << 7;
  const size_t z = blockIdx.z;
  const size_t zlo = z & (((size_t)1 << zshift) - 1);
  A += (z >> zshift) * zAh + zlo * zAl;
  B += (z >> zshift) * zBh + zlo * zBl;
  C += z * zC;
  if (EXP) lpart += z * zL;

  // staging geometry
  const int srow8 = lane >> 3;  // row within 8-row chunk
  const int g8 = (lane & 4) | ((lane & 3) ^ ((lane >> 4) & 3));
  const bf16* gA[4];
  const bf16* gB[4];
  bf16* lA[4];
  bf16* lB[4];
#pragma unroll
  for (int j = 0; j < 4; ++j) {
    const int c = w + 4 * j;
    gA[j] = A + (size_t)(m0 + c * 8 + srow8) * lda + g8 * 8;
    gB[j] = B + (size_t)(n0 + c * 8 + srow8) * ldb + g8 * 8;
    lA[j] = As + c * 512;
    lB[j] = Bs + c * 512;
  }

  // fragment geometry
  const int m15 = lane & 15, quad = lane >> 4;
  const int fq = quad ^ ((m15 >> 1) & 3);
  const bf16* pA = As + (size_t)(((w >> 1) << 6) + m15) * 64 + fq * 8;
  const bf16* pB = Bs + (size_t)(((w & 1) << 6) + m15) * 64 + fq * 8;

  f32x4 acc[4][4];
#pragma unroll
  for (int mi = 0; mi < 4; ++mi)
#pragma unroll
    for (int ni = 0; ni < 4; ++ni) acc[mi][ni] = (f32x4)(0.0f);

  for (int k0 = 0; k0 < K; k0 += 64) {
#pragma unroll
    for (int j = 0; j < 4; ++j) {
      load_lds16(gA[j], lA[j]);
      load_lds16(gB[j], lB[j]);
      gA[j] += 64;
      gB[j] += 64;
    }
    __syncthreads();
    bf16x8 av[4][2], bv[4][2];
#pragma unroll
    for (int mi = 0; mi < 4; ++mi)
#pragma unroll
      for (int sub = 0; sub < 2; ++sub) {
        av[mi][sub] = *(const bf16x8*)(pA + mi * 1024 + sub * 32);
        bv[mi][sub] = *(const bf16x8*)(pB + mi * 1024 + sub * 32);
      }
#pragma unroll
    for (int sub = 0; sub < 2; ++sub)
#pragma unroll
      for (int mi = 0; mi < 4; ++mi)
#pragma unroll
        for (int ni = 0; ni < 4; ++ni)
          acc[mi][ni] = __builtin_amdgcn_mfma_f32_16x16x32_bf16(
              av[mi][sub], bv[ni][sub], acc[mi][ni], 0, 0, 0);
    __syncthreads();
  }

  const int crow = m0 + ((w >> 1) << 6) + quad * 4;
  const int ccol = n0 + ((w & 1) << 6) + m15;
  float rs[4][4] = {};
#pragma unroll
  for (int ni = 0; ni < 4; ++ni) {
    const int col = ccol + ni * 16;
    const float bb = bias ? bias[col] : 0.0f;
#pragma unroll
    for (int mi = 0; mi < 4; ++mi) {
#pragma unroll
      for (int i = 0; i < 4; ++i) {
        const int row = crow + mi * 16 + i;
        float v = acc[mi][ni][i] * scale + bb;
        if constexpr (EXP) {
          v = __expf(v);
          rs[mi][i] += v;
        }
        if constexpr (sizeof(OutT) == 2)
          C[(size_t)row * ldc + col] = __float2bfloat16(v);
        else
          C[(size_t)row * ldc + col] = v;
      }
    }
  }
  if constexpr (EXP) {
    const int ch = ((int)blockIdx.x << 1) | (w & 1);
#pragma unroll
    for (int mi = 0; mi < 4; ++mi)
#pragma unroll
      for (int i = 0; i < 4; ++i) {
        float sv = rs[mi][i];
        sv += __shfl_xor(sv, 1);
        sv += __shfl_xor(sv, 2);
        sv += __shfl_xor(sv, 4);
        sv += __shfl_xor(sv, 8);
        if (m15 == 0)
          lpart[(size_t)ch * 4096 + crow + mi * 16 + i] = sv;
      }
  }
}

// ---------------------------------------------------------------------------
// residual + LayerNorm from split-K PV partials and lpart row sums.
// FUSE=true : emit 9 bf16 KAN basis channels directly (no x buffer).
// ---------------------------------------------------------------------------
template <bool FUSE>
__global__ __launch_bounds__(256) void resid_ln_kernel(
    const float* __restrict__ attp, const float* __restrict__ lpart,
    const float* __restrict__ tok, const float* __restrict__ gamma,
    const float* __restrict__ beta, float* __restrict__ xout,
    bf16* __restrict__ basis, int vIdx) {
  __shared__ float red[4];
  __shared__ float sinvl;
  __shared__ __align__(16) bf16 st[2304];  // 256 elems x 9 channels
  const int n = (int)blockIdx.x;  // 0..8191 ; b = n>>12
  const int d = (int)threadIdx.x;
  const int b = n >> 12, r = n & 4095;
  float ls = 0.f;
  if (d < 64) ls = lpart[((size_t)(b * 64 + d)) * 4096 + r];
  ls = wave_sum(ls);
  if (d == 0) sinvl = 1.0f / ls;
  const size_t abase = (size_t)(b * 4) * 1048576 + (size_t)r * 256 + d;
  const float asum = attp[abase] + attp[abase + 1048576] +
                     attp[abase + 2097152] + attp[abase + 3145728];
  __syncthreads();
  const float y = asum * sinvl + tok[(size_t)n * 256 + d];
  float s = wave_sum(y);
  if ((d & 63) == 0) red[d >> 6] = s;
  __syncthreads();
  const float mu = (red[0] + red[1] + red[2] + red[3]) * (1.0f / 256.0f);
  __syncthreads();
  const float c = y - mu;
  float s2 = wave_sum(c * c);
  if ((d & 63) == 0) red[d >> 6] = s2;
  __syncthreads();
  const float var = (red[0] + red[1] + red[2] + red[3]) * (1.0f / 256.0f);
  const float rstd = rsqrtf(var + 1e-5f);
  const float val = c * rstd * gamma[d] + beta[d];
  if constexpr (!FUSE) {
    xout[(size_t)n * 768 + vIdx * 256 + d] = val;
  } else {
#pragma unroll
    for (int f = 0; f < 8; ++f)
      st[d * 9 + f] = __float2bfloat16(b3_cardinal(val, 5.5f - (float)f));
    st[d * 9 + 8] = __float2bfloat16(val / (1.0f + __expf(-val)));
    __syncthreads();
    float4* gb = (float4*)((char*)basis + (size_t)n * 13824 + vIdx * 4608);
    const float4* sb = (const float4*)st;
    gb[d] = sb[d];
    if (d < 32) gb[256 + d] = sb[256 + d];
  }
}

// ---------------------------------------------------------------------------
__global__ __launch_bounds__(256) void prep_w(
    const float* __restrict__ bw, const float* __restrict__ sw,
    const float* __restrict__ scaler, bf16* __restrict__ Wmat) {
  const int o = blockIdx.x;
  for (int ii = 0; ii < 3; ++ii) {
    const int i = ii * 256 + (int)threadIdx.x;
    const float s = scaler[(size_t)o * 768 + i];
    bf16* p = Wmat + (size_t)o * 6912 + i * 9;
    const float* swp = sw + ((size_t)o * 768 + i) * 8;
#pragma unroll
    for (int f = 0; f < 8; ++f) p[f] = __float2bfloat16(swp[f] * s);
    p[8] = __float2bfloat16(bw[(size_t)o * 768 + i]);
  }
}

__global__ __launch_bounds__(256) void prep_qkvw(
    const float* __restrict__ wq, const float* __restrict__ wk,
    const float* __restrict__ wv, const float* __restrict__ bq,
    const float* __restrict__ bk, const float* __restrict__ bv,
    bf16* __restrict__ wqkvb, float* __restrict__ bqkv) {
  const int idx = blockIdx.x * 256 + (int)threadIdx.x;
  const int row = idx >> 8, col = idx & 255;
  const float* src = row < 256 ? wq : (row < 512 ? wk : wv);
  wqkvb[idx] = __float2bfloat16(src[((row & 255) << 8) + col]);
  if (idx < 768)
    bqkv[idx] = idx < 256 ? bq[idx] : (idx < 512 ? bk[idx - 256] : bv[idx - 512]);
}

__global__ __launch_bounds__(256) void cast_tok3(
    const float4* __restrict__ t0, const float4* __restrict__ t1,
    const float4* __restrict__ t2, bf16* __restrict__ dst) {
  const int vv = blockIdx.y;
  const float4* src = vv == 0 ? t0 : (vv == 1 ? t1 : t2);
  const int idx = blockIdx.x * 256 + (int)threadIdx.x;
  const float4 val = src[idx];
  bf16* p = dst + (size_t)vv * 2097152 + (size_t)idx * 4;
  p[0] = __float2bfloat16(val.x);
  p[1] = __float2bfloat16(val.y);
  p[2] = __float2bfloat16(val.z);
  p[3] = __float2bfloat16(val.w);
}

// vT[z][d][s] = qkv[z*4096+s][512+d]
__global__ __launch_bounds__(256) void transpose_v(
    const bf16* __restrict__ qkv, bf16* __restrict__ vT) {
  __shared__ bf16 tle[64][65];
  const int s0 = blockIdx.x << 6, d0 = blockIdx.y << 6, z = blockIdx.z;
  const int tid = (int)threadIdx.x;
  const int c = tid & 63, rr = tid >> 6;
  for (int r = 0; r < 64; r += 4)
    tle[r + rr][c] = qkv[(size_t)(z * 4096 + s0 + r + rr) * 768 + 512 + d0 + c];
  __syncthreads();
  for (int r = 0; r < 64; r += 4)
    vT[(size_t)z * 1048576 + (size_t)(d0 + r + rr) * 4096 + s0 + c] =
        tle[c][r + rr];
}

// ---------------------------------------------------------------------------
// fallback basis: basis[n][i*9+f] from x (Cox-de-Boor, proven R6)
// ---------------------------------------------------------------------------
__global__ __launch_bounds__(256) void basis_kernel(
    const float* __restrict__ x, bf16* __restrict__ basis) {
  const int i = blockIdx.x * 256 + (int)threadIdx.x;  // 0..767
  const int n = blockIdx.y;
  const float xv = x[(size_t)n * 768 + i];
  float b[11];
#pragma unroll
  for (int m = 0; m < 11; ++m) {
    const float g0 = 0.4f * (float)(m - 3) - 1.0f;
    const float g1 = 0.4f * (float)(m - 2) - 1.0f;
    b[m] = (xv >= g0 && xv < g1) ? 1.0f : 0.0f;
  }
#pragma unroll
  for (int k = 1; k <= 3; ++k) {
    const float inv = 1.0f / (0.4f * (float)k);
#pragma unroll
    for (int m = 0; m + k < 11; ++m) {
      const float gm = 0.4f * (float)(m - 3) - 1.0f;
      const float gmk1 = 0.4f * (float)(m + k - 2) - 1.0f;
      b[m] = (xv - gm) * inv * b[m] + (gmk1 - xv) * inv * b[m + 1];
    }
  }
  bf16* p = basis + (size_t)n * 6912 + i * 9;
#pragma unroll
  for (int f = 0; f < 8; ++f) p[f] = __float2bfloat16(b[f]);
  p[8] = __float2bfloat16(xv / (1.0f + __expf(-xv)));
}

__global__ __launch_bounds__(256) void combine4_kernel(
    const float4* __restrict__ p, float4* __restrict__ out) {
  const int idx = blockIdx.x * 256 + (int)threadIdx.x;
  const float4 a = p[idx];
  const float4 b = p[idx + 524288];
  const float4 c = p[idx + 1048576];
  const float4 d = p[idx + 1572864];
  out[idx] =
      make_float4(a.x + b.x + c.x + d.x, a.y + b.y + c.y + d.y,
                  a.z + b.z + c.z + d.z, a.w + b.w + c.w + d.w);
}

__global__ __launch_bounds__(256) void combine6_kernel(
    const float4* __restrict__ p, float4* __restrict__ out) {
  const int idx = blockIdx.x * 256 + (int)threadIdx.x;
  float4 s = p[idx];
#pragma unroll
  for (int j = 1; j < 6; ++j) {
    const float4 a = p[idx + (size_t)j * 524288];
    s.x += a.x;
    s.y += a.y;
    s.z += a.z;
    s.w += a.w;
  }
  out[idx] = s;
}

// ---------------------------------------------------------------------------
extern "C" void kernel_launch(void* const* d_in, const int* in_sizes, int n_in,
                              void* d_out, int out_size, void* d_ws,
                              size_t ws_size, hipStream_t stream) {
  const float* tok[3] = {(const float*)d_in[0], (const float*)d_in[1],
                         (const float*)d_in[2]};
  const float* wq = (const float*)d_in[3];
  const float* bq = (const float*)d_in[4];
  const float* wk = (const float*)d_in[5];
  const float* bk = (const float*)d_in[6];
  const float* wv = (const float*)d_in[7];
  const float* bv = (const float*)d_in[8];
  // d_in[9] view_emb unused (softmax-invariant)
  const float* lng[3] = {(const float*)d_in[10], (const float*)d_in[12],
                         (const float*)d_in[14]};
  const float* lnb[3] = {(const float*)d_in[11], (const float*)d_in[13],
                         (const float*)d_in[15]};
  const float* bw = (const float*)d_in[16];
  const float* sw = (const float*)d_in[17];
  const float* scaler = (const float*)d_in[18];

  // layout (bytes) — identical to R9-proven:
  //   tokb @0 (12.58M) | qkv @12,582,912 (37.75M) | vT @50,331,648 (12.58M)
  //   Pb @62,914,560 (67.11M) | lpart @130,023,424 (2.10M)
  //   attp @132,120,576 (33.55M)
  // fused : basis @165,675,008 (113.25M), Wmat @278,921,216; pout (KAN z=6,
  //         50.33M) aliases Pb (dead after last PV).
  // fallback: x @165,675,008, basis aliases [0,113.25M), Wmat @190,840,832;
  //         pout (z=4) aliases attp.
  const bool fused = ws_size >= 282856448ull;
  char* w8 = (char*)d_ws;
  bf16* tokb = (bf16*)(w8 + 0);
  bf16* qkv = (bf16*)(w8 + 12582912);
  bf16* vT = (bf16*)(w8 + 50331648);
  bf16* Pb = (bf16*)(w8 + 62914560);
  float* lpart = (float*)(w8 + 130023424);
  float* attp = (float*)(w8 + 132120576);
  float* x;
  bf16* basis;
  bf16* Wmat;
  float* pout;
  if (fused) {
    x = nullptr;
    basis = (bf16*)(w8 + 165675008);
    Wmat = (bf16*)(w8 + 278921216);
    pout = (float*)Pb;  // 6 x 8.39 MB = 50.33 MB <= 67.11 MB, Pb dead
  } else {
    x = (float*)(w8 + 165675008);
    basis = (bf16*)(w8 + 0);
    Wmat = (bf16*)(w8 + 190840832);
    pout = attp;  // 4 x 8.39 MB, attp dead
  }
  bf16* wqkvb = (bf16*)((char*)Wmat + 3538944);
  float* bqkv = (float*)((char*)wqkvb + 393216);

  prep_w<<<256, 256, 0, stream>>>(bw, sw, scaler, Wmat);
  prep_qkvw<<<768, 256, 0, stream>>>(wq, wk, wv, bq, bk, bv, wqkvb, bqkv);
  cast_tok3<<<dim3(2048, 3), 256, 0, stream>>>(
      (const float4*)tok[0], (const float4*)tok[1], (const float4*)tok[2],
      tokb);

  // QKV all views: [24576,256] @ [768,256]^T + bias -> qkv bf16
  mfma_gemm_bt<bf16, false><<<dim3(6, 192, 1), 256, 0, stream>>>(
      tokb, wqkvb, bqkv, qkv, nullptr, 256, 256, 256, 768, 1, 0, 0, 0, 0, 0,
      0, 1.0f);
  transpose_v<<<dim3(64, 4, 6), 256, 0, stream>>>(qkv, vT);

  for (int v = 0; v < 3; ++v) {
    const bf16* qb = qkv + (size_t)(2 * v) * 4096 * 768;
    // scores both batches (z=2): P = exp(q@k^T/16) bf16 + lpart partials
    mfma_gemm_bt<bf16, true><<<dim3(32, 32, 2), 256, 0, stream>>>(
        qb, qb + 256, nullptr, Pb, lpart, 256, 768, 768, 4096, 1, 0, 3145728,
        0, 3145728, 16777216, 262144, 0.0625f);
    // PV split-K=4 x batch (z=8): attp[z] = P-slice @ vT-slice^T
    mfma_gemm_bt<float, false><<<dim3(2, 32, 8), 256, 0, stream>>>(
        Pb, vT + (size_t)(2 * v) * 1048576, nullptr, attp, nullptr, 1024,
        4096, 4096, 256, 2, 16777216, 1024, 1048576, 1024, 1048576, 0, 1.0f);
    if (fused)
      resid_ln_kernel<true><<<8192, 256, 0, stream>>>(
          attp, lpart, tok[v], lng[v], lnb[v], nullptr, basis, v);
    else
      resid_ln_kernel<false><<<8192, 256, 0, stream>>>(
          attp, lpart, tok[v], lng[v], lnb[v], x, nullptr, v);
  }

  if (fused) {
    // KAN split-K=6 (z=6, 768 blocks = 3/CU): slice K=1152
    mfma_gemm_bt<float, false><<<dim3(2, 64, 6), 256, 0, stream>>>(
        basis, Wmat, nullptr, pout, nullptr, 1152, 6912, 6912, 256, 3, 0,
        1152, 0, 1152, 2097152, 0, 1.0f);
    combine6_kernel<<<2048, 256, 0, stream>>>((const float4*)pout,
                                              (float4*)d_out);
  } else {
    basis_kernel<<<dim3(3, 8192), 256, 0, stream>>>(x, basis);
    mfma_gemm_bt<float, false><<<dim3(2, 64, 4), 256, 0, stream>>>(
        basis, Wmat, nullptr, pout, nullptr, 1728, 6912, 6912, 256, 2, 0,
        1728, 0, 1728, 2097152, 0, 1.0f);
    combine4_kernel<<<2048, 256, 0, stream>>>((const float4*)pout,
                                              (float4*)d_out);
  }
}